// Round 2
// baseline (3075.668 us; speedup 1.0000x reference)
//
#include <hip/hip_runtime.h>
#include <stdint.h>

// BayesLSTM R1: fused sample+GEMM per stage.
//   prologue: precompute elv = exp(0.5*logvar) for all params; zero state.
//   129 step launches; launch t = layer0 step t (blocks 0..127) + layer1
//   step t-1 (blocks 128..255). Each block owns 2 output columns j (x4 gate
//   slices), samples its 8 x Ktot weight stripe straight into LDS (threefry
//   keys precomputed on HOST, passed as args), multiplies against the 64xKtot
//   input staged in chunked double-buffered LDS, k-split-16 partials, then
//   reduces + activates. No sampled weights ever touch global memory.

typedef unsigned int u32;

#define Bn 64
#define Tn 128
#define INn 64
#define Hn 256
#define Gn 1024
#define BH (Bn * Hn)

#define OFF_ELV_WIH0 0
#define OFF_ELV_WHH0 65536
#define OFF_ELV_WIH1 327680
#define OFF_ELV_WHH1 589824
#define OFF_ELV_B    851968            // bih0,bhh0,bih1,bhh1 (4*1024)
#define OFF_RING     856064
#define OFF_H0       (OFF_RING + 2 * BH)
#define OFF_H1       (OFF_H0 + 2 * BH)
#define OFF_C0       (OFF_H1 + 2 * BH)
#define OFF_C1       (OFF_C0 + BH)
#define WS_FLOATS    (OFF_C1 + BH)     // 987136 floats = 3.95 MiB
#define STATE_FLOATS (WS_FLOATS - OFF_RING)
#define OUT_HN       (Bn * Tn * Hn)

struct KP { u32 a, b; };
struct StepKeys { u32 k[16]; };  // [layer][kw.a,kw.b,ku.a,ku.b,kbi.a,kbi.b,kbh.a,kbh.b]

// Threefry-2x32, 20 rounds — matches jax/_src/prng.py exactly.
__host__ __device__ __forceinline__ KP tf(u32 k0, u32 k1, u32 x0, u32 x1) {
  u32 ks2 = k0 ^ k1 ^ 0x1BD11BDAu;
  x0 += k0; x1 += k1;
#define TFR(r) { x0 += x1; x1 = (x1 << (r)) | (x1 >> (32 - (r))); x1 ^= x0; }
  TFR(13) TFR(15) TFR(26) TFR(6)
  x0 += k1;  x1 += ks2 + 1u;
  TFR(17) TFR(29) TFR(16) TFR(24)
  x0 += ks2; x1 += k0 + 2u;
  TFR(13) TFR(15) TFR(26) TFR(6)
  x0 += k0;  x1 += k1 + 3u;
  TFR(17) TFR(29) TFR(16) TFR(24)
  x0 += k1;  x1 += ks2 + 4u;
  TFR(13) TFR(15) TFR(26) TFR(6)
  x0 += ks2; x1 += k0 + 5u;
#undef TFR
  KP o; o.a = x0; o.b = x1; return o;
}

// bits -> N(0,1) matching jax.random.normal f32 (erfinv = XLA/Giles poly).
__device__ __forceinline__ float n01(u32 bits) {
  float f = __uint_as_float((bits >> 9) | 0x3f800000u) - 1.0f;
  float u = fmaxf(-0.99999994f, f * 2.0f - 0.99999994f);
  float w = -log1pf(-u * u);
  float p;
  if (w < 5.0f) {
    float z = w - 2.5f;
    p = 2.81022636e-08f;
    p = 3.43273939e-07f  + p * z;
    p = -3.5233877e-06f  + p * z;
    p = -4.39150654e-06f + p * z;
    p = 0.00021858087f   + p * z;
    p = -0.00125372503f  + p * z;
    p = -0.00417768164f  + p * z;
    p = 0.246640727f     + p * z;
    p = 1.50140941f      + p * z;
  } else {
    float z = sqrtf(w) - 3.0f;
    p = -0.000200214257f;
    p = 0.000100950558f  + p * z;
    p = 0.00134934322f   + p * z;
    p = -0.00367342844f  + p * z;
    p = 0.00573950773f   + p * z;
    p = -0.0076224613f   + p * z;
    p = 0.00943887047f   + p * z;
    p = 1.00167406f      + p * z;
    p = 2.83297682f      + p * z;
  }
  return 1.41421356237f * (p * u);
}

// LDS pool carve (bytes): [wbuf 8x516 f32 =16512][inb 2x64x68 f32 =34816]
// gpart 16x520 f32 = 33280 ALIASES [0,33280) (wbuf+inb dead by then).
// bias2 (8 f32) lives at 51328, beyond gpart's extent.
#define POOL_BYTES 51360
#define WBUF_OFF   0
#define INB_OFF    16512
#define BIAS_OFF   51328

template<int LAYER>
__device__ void step_body(
    const float* __restrict__ x,
    const float* __restrict__ wihmu, const float* __restrict__ whhmu,
    const float* __restrict__ bihmu, const float* __restrict__ bhhmu,
    float* __restrict__ ws, float* __restrict__ out, int t, StepKeys keys,
    char* pool)
{
  constexpr int Kin  = LAYER ? Hn : INn;
  constexpr int Ktot = Kin + Hn;      // 512 or 320
  constexpr int nch  = Ktot / 64;     // 8 or 5
  const int tid = threadIdx.x;
  const int lb  = blockIdx.x & 127;
  const int j0  = lb * 2;
  const int ts  = LAYER ? (t - 1) : t;
  const int tsb = ts & 1;

  float* wbuf  = (float*)(pool + WBUF_OFF);   // [8][516]
  float* inb   = (float*)(pool + INB_OFF);    // [2][64][68]
  float* gpart = (float*)(pool + 0);          // [16][520], aliases wbuf+inb
  float* bias2 = (float*)(pool + BIAS_OFF);   // [8]

  const float* elv_ih  = ws + (LAYER ? OFF_ELV_WIH1 : OFF_ELV_WIH0);
  const float* elv_hh  = ws + (LAYER ? OFF_ELV_WHH1 : OFF_ELV_WHH0);
  const float* belv_ih = ws + OFF_ELV_B + LAYER * 2048;
  const float* belv_hh = belv_ih + 1024;
  const float* hprev   = ws + (LAYER ? OFF_H1 : OFF_H0) + tsb * BH;
  const float* ring    = ws + OFF_RING + tsb * BH;

  // ---- input chunk loaders (global -> regs -> swizzled LDS) -------------
  // f = tid + 256*m: row b = f>>4, 16B segment seg = f&15.
  // LDS column swizzle: quad stored at col 4*(seg ^ ((b>>3)&7)) — makes the
  // FMA-phase reads (8 b-rows x same k-quad) hit 8 distinct bank-quads.
  auto src_addr = [&](int c, int b, int q4) -> const float* {
    if (LAYER == 0) {
      if (c == 0) return x + (b * Tn + ts) * INn + q4;
      return hprev + b * Hn + (c - 1) * 64 + q4;
    } else {
      if (c < 4) return ring + b * Hn + c * 64 + q4;
      return hprev + b * Hn + (c - 4) * 64 + q4;
    }
  };
  float4 pf[4];
  auto stage_load = [&](int c) {
    #pragma unroll
    for (int m = 0; m < 4; ++m) {
      int f = tid + 256 * m, b = f >> 4, q4 = (f & 15) * 4;
      pf[m] = *(const float4*)src_addr(c, b, q4);
    }
  };
  auto stage_write = [&](int buf) {
    #pragma unroll
    for (int m = 0; m < 4; ++m) {
      int f = tid + 256 * m, b = f >> 4, seg = f & 15;
      int col = 4 * (seg ^ ((b >> 3) & 7));
      *(float4*)&inb[((buf << 6) + b) * 68 + col] = pf[m];
    }
  };

  // ---- phase 1: issue chunk-0 loads, then sample weights into LDS -------
  stage_load(0);

  const u32 kwa = keys.k[LAYER * 8 + 0], kwb = keys.k[LAYER * 8 + 1];
  const u32 kua = keys.k[LAYER * 8 + 2], kub = keys.k[LAYER * 8 + 3];
  #pragma unroll
  for (int it = 0; it < (Ktot + 255) / 256; ++it) {
    int k = tid + it * 256;
    if (k < Ktot) {
      bool iswih = k < Kin;
      u32 ka = iswih ? kwa : kua, kb = iswih ? kwb : kub;
      const float* mup  = iswih ? wihmu  : whhmu;
      const float* elvp = iswih ? elv_ih : elv_hh;
      int kk = iswih ? k : k - Kin;
      int kstride = iswih ? Kin : Hn;
      #pragma unroll
      for (int gi = 0; gi < 8; ++gi) {           // gi = jj*4 + s
        int g = (gi & 3) * Hn + j0 + (gi >> 2);
        int i = g * kstride + kk;
        KP r = tf(ka, kb, 0u, (u32)i);
        wbuf[gi * 516 + k] = mup[i] + elvp[i] * n01(r.a ^ r.b);
      }
    }
  }
  if (tid < 8) {
    int g = (tid & 3) * Hn + j0 + (tid >> 2);
    KP rb = tf(keys.k[LAYER * 8 + 4], keys.k[LAYER * 8 + 5], 0u, (u32)g);
    KP rh = tf(keys.k[LAYER * 8 + 6], keys.k[LAYER * 8 + 7], 0u, (u32)g);
    bias2[tid] = bihmu[g] + belv_ih[g] * n01(rb.a ^ rb.b)
               + bhhmu[g] + belv_hh[g] * n01(rh.a ^ rh.b);
  }
  stage_write(0);
  __syncthreads();

  // ---- phase 2: chunked FMA, k-split 16, per-thread 8b x 4s tile --------
  const int kq = tid >> 4;          // 0..15 : k-quad within chunk
  const int bp = (tid >> 1) & 7;    // 0..7  : batch group (8 rows)
  const int jj = tid & 1;           // 0..1  : which j column
  const int colq = 4 * (kq ^ bp);   // swizzled inb column (holds quad kq)

  float acc[8][4];
  #pragma unroll
  for (int r = 0; r < 8; ++r)
    acc[r][0] = acc[r][1] = acc[r][2] = acc[r][3] = 0.f;

  #pragma unroll
  for (int c = 0; c < nch; ++c) {
    if (c + 1 < nch) stage_load(c + 1);
    float4 w4[4];
    #pragma unroll
    for (int s = 0; s < 4; ++s)
      w4[s] = *(const float4*)&wbuf[(jj * 4 + s) * 516 + c * 64 + kq * 4];
    #pragma unroll
    for (int r = 0; r < 8; ++r) {
      float4 in4 = *(const float4*)&inb[((( c & 1) << 6) + bp * 8 + r) * 68 + colq];
      #pragma unroll
      for (int s = 0; s < 4; ++s)
        acc[r][s] += in4.x * w4[s].x + in4.y * w4[s].y
                   + in4.z * w4[s].z + in4.w * w4[s].w;
    }
    if (c + 1 < nch) stage_write((c + 1) & 1);
    __syncthreads();
  }

  // ---- phase 3: k-partials to LDS (bp-swizzled), reduce, activate -------
  // gpart[kq][col4*4..+3]; col4 = (16bp + 2r + jj) ^ bp spreads the bp axis
  // (which is 0 mod 32 banks in a linear layout) across bank-quads.
  #pragma unroll
  for (int r = 0; r < 8; ++r) {
    float4 v = {acc[r][0], acc[r][1], acc[r][2], acc[r][3]};
    int col4 = (bp * 16 + r * 2 + jj) ^ bp;
    *(float4*)&gpart[kq * 520 + col4 * 4] = v;
  }
  __syncthreads();

  if (tid < 128) {
    const int b = tid >> 1, j2 = tid & 1;
    const int rbp = b >> 3, rr = b & 7;
    const int col4 = (rbp * 16 + rr * 2 + j2) ^ rbp;
    float4 gq = {0.f, 0.f, 0.f, 0.f};
    #pragma unroll
    for (int q = 0; q < 16; ++q) {
      float4 p = *(const float4*)&gpart[q * 520 + col4 * 4];
      gq.x += p.x; gq.y += p.y; gq.z += p.z; gq.w += p.w;
    }
    const int j = j0 + j2;
    float gI = gq.x + bias2[j2 * 4 + 0];
    float gF = gq.y + bias2[j2 * 4 + 1];
    float gG = gq.z + bias2[j2 * 4 + 2];
    float gO = gq.w + bias2[j2 * 4 + 3];

    float* cst = ws + (LAYER ? OFF_C1 : OFF_C0);
    float cp = cst[b * Hn + j];
    float si = 1.f / (1.f + expf(-gI));
    float sf = 1.f / (1.f + expf(-gF));
    float so = 1.f / (1.f + expf(-gO));
    float cn = sf * cp + si * tanhf(gG);
    float hn = so * tanhf(cn);
    cst[b * Hn + j] = cn;
    float* hnx = ws + (LAYER ? OFF_H1 : OFF_H0) + ((ts + 1) & 1) * BH;
    hnx[b * Hn + j] = hn;
    if (LAYER == 0) {
      ws[OFF_RING + tsb * BH + b * Hn + j] = hn;
      if (ts == Tn - 1) {
        out[OUT_HN + b * Hn + j] = hn;                 // h_n[0]
        out[OUT_HN + 2 * BH + b * Hn + j] = cn;        // c_n[0]
      }
    } else {
      out[b * (Tn * Hn) + ts * Hn + j] = hn;           // output[b][ts][j]
      if (ts == Tn - 1) {
        out[OUT_HN + BH + b * Hn + j] = hn;            // h_n[1]
        out[OUT_HN + 3 * BH + b * Hn + j] = cn;        // c_n[1]
      }
    }
  }
}

__global__ __launch_bounds__(256) void bayes_lstm_step(
    const float* __restrict__ x,
    const float* __restrict__ wihmu0, const float* __restrict__ whhmu0,
    const float* __restrict__ bihmu0, const float* __restrict__ bhhmu0,
    const float* __restrict__ wihmu1, const float* __restrict__ whhmu1,
    const float* __restrict__ bihmu1, const float* __restrict__ bhhmu1,
    float* __restrict__ ws, float* __restrict__ out, int t, StepKeys keys)
{
  __shared__ __align__(16) char pool[POOL_BYTES];
  if ((blockIdx.x >> 7) == 0) {
    if (t >= Tn) return;
    step_body<0>(x, wihmu0, whhmu0, bihmu0, bhhmu0, ws, out, t, keys, pool);
  } else {
    if (t < 1) return;
    step_body<1>(x, wihmu1, whhmu1, bihmu1, bhhmu1, ws, out, t, keys, pool);
  }
}

__global__ __launch_bounds__(256) void bayes_lstm_prologue(
    const float* __restrict__ wihlv0, const float* __restrict__ whhlv0,
    const float* __restrict__ bihlv0, const float* __restrict__ bhhlv0,
    const float* __restrict__ wihlv1, const float* __restrict__ whhlv1,
    const float* __restrict__ bihlv1, const float* __restrict__ bhhlv1,
    float* __restrict__ ws)
{
  const int gt = blockIdx.x * 256 + threadIdx.x;
  const int stride = gridDim.x * 256;
  for (int i = gt; i < 65536; i += stride)
    ws[OFF_ELV_WIH0 + i] = expf(0.5f * wihlv0[i]);
  for (int i = gt; i < 262144; i += stride) {
    ws[OFF_ELV_WHH0 + i] = expf(0.5f * whhlv0[i]);
    ws[OFF_ELV_WIH1 + i] = expf(0.5f * wihlv1[i]);
    ws[OFF_ELV_WHH1 + i] = expf(0.5f * whhlv1[i]);
  }
  for (int i = gt; i < 1024; i += stride) {
    ws[OFF_ELV_B + i]        = expf(0.5f * bihlv0[i]);
    ws[OFF_ELV_B + 1024 + i] = expf(0.5f * bhhlv0[i]);
    ws[OFF_ELV_B + 2048 + i] = expf(0.5f * bihlv1[i]);
    ws[OFF_ELV_B + 3072 + i] = expf(0.5f * bhhlv1[i]);
  }
  for (int i = gt; i < STATE_FLOATS; i += stride)
    ws[OFF_RING + i] = 0.f;
}

extern "C" void kernel_launch(void* const* d_in, const int* in_sizes, int n_in,
                              void* d_out, int out_size, void* d_ws, size_t ws_size,
                              hipStream_t stream) {
  (void)in_sizes; (void)n_in; (void)out_size;
  if (ws_size < (size_t)WS_FLOATS * sizeof(float)) return;  // need 3.95 MiB

  const float* x      = (const float*)d_in[0];
  const float* wihmu0 = (const float*)d_in[1];
  const float* wihlv0 = (const float*)d_in[2];
  const float* whhmu0 = (const float*)d_in[3];
  const float* whhlv0 = (const float*)d_in[4];
  const float* bihmu0 = (const float*)d_in[5];
  const float* bihlv0 = (const float*)d_in[6];
  const float* bhhmu0 = (const float*)d_in[7];
  const float* bhhlv0 = (const float*)d_in[8];
  const float* wihmu1 = (const float*)d_in[9];
  const float* wihlv1 = (const float*)d_in[10];
  const float* whhmu1 = (const float*)d_in[11];
  const float* whhlv1 = (const float*)d_in[12];
  const float* bihmu1 = (const float*)d_in[13];
  const float* bihlv1 = (const float*)d_in[14];
  const float* bhhmu1 = (const float*)d_in[15];
  const float* bhhlv1 = (const float*)d_in[16];
  float* ws  = (float*)d_ws;
  float* out = (float*)d_out;

  bayes_lstm_prologue<<<dim3(256), dim3(256), 0, stream>>>(
      wihlv0, whhlv0, bihlv0, bhhlv0, wihlv1, whhlv1, bihlv1, bhhlv1, ws);

  for (int t = 0; t <= Tn; ++t) {
    StepKeys keys;
    for (int l = 0; l < 2; ++l) {
      int ts = l ? t - 1 : t;
      if (ts < 0) ts = 0;
      if (ts >= Tn) ts = Tn - 1;   // clamped keys are never consumed
      KP lk  = tf(0u, 42u, 0u, (u32)l);
      KP kt  = tf(lk.a, lk.b, 0u, (u32)ts);
      KP kw  = tf(kt.a, kt.b, 0u, 0u);
      KP ku  = tf(kt.a, kt.b, 0u, 1u);
      KP kbi = tf(kt.a, kt.b, 0u, 2u);
      KP kbh = tf(kt.a, kt.b, 0u, 3u);
      keys.k[l * 8 + 0] = kw.a;  keys.k[l * 8 + 1] = kw.b;
      keys.k[l * 8 + 2] = ku.a;  keys.k[l * 8 + 3] = ku.b;
      keys.k[l * 8 + 4] = kbi.a; keys.k[l * 8 + 5] = kbi.b;
      keys.k[l * 8 + 6] = kbh.a; keys.k[l * 8 + 7] = kbh.b;
    }
    bayes_lstm_step<<<dim3(256), dim3(256), 0, stream>>>(
        x, wihmu0, whhmu0, bihmu0, bhhmu0,
        wihmu1, whhmu1, bihmu1, bhhmu1, ws, out, t, keys);
  }
}